// Round 7
// baseline (439.924 us; speedup 1.0000x reference)
//
#include <hip/hip_runtime.h>
#include <math.h>

typedef _Float16 f16;
typedef _Float16 f16x8 __attribute__((ext_vector_type(8)));
typedef float f32x4 __attribute__((ext_vector_type(4)));

#define DIM 1024
enum { EPI_K = 0, EPI_V = 1 };

__device__ __forceinline__ float phi_f(float x) {
  return x > 0.f ? x + 1.f : __expf(x);  // elu(x)+1
}

// global -> LDS direct DMA, 16 B per lane, wave-uniform LDS base.
typedef __attribute__((address_space(1))) const void gconst_t;
typedef __attribute__((address_space(3))) void lds_t;
__device__ __forceinline__ void g2l16(const void* g, void* l) {
  __builtin_amdgcn_global_load_lds((gconst_t*)(uintptr_t)g, (lds_t*)(uintptr_t)l, 16, 0, 0);
}

// XCD-bijective swizzle for grid (8, MT): XCD x gets MT/8 consecutive m-tiles x all 8 n-tiles.
template <int MT>
__device__ __forceinline__ void swz(int& nb, int& mb) {
  int flat = blockIdx.y * 8 + blockIdx.x;
  int wk = (flat & 7) * MT + (flat >> 3);
  nb = wk & 7;
  mb = wk >> 3;
}

// ---------------- fp32 -> fp16 convert (weights) ----------------
__global__ __launch_bounds__(256) void cvt8(const float* __restrict__ src,
                                            f16* __restrict__ dst) {
  size_t i = ((size_t)blockIdx.x * 256 + threadIdx.x) * 8;
  float4 a = *(const float4*)(src + i);
  float4 b = *(const float4*)(src + i + 4);
  union { f16 h[8]; uint4 u; } p;
  p.h[0] = (f16)a.x; p.h[1] = (f16)a.y; p.h[2] = (f16)a.z; p.h[3] = (f16)a.w;
  p.h[4] = (f16)b.x; p.h[5] = (f16)b.y; p.h[6] = (f16)b.z; p.h[7] = (f16)b.w;
  *(uint4*)(dst + i) = p.u;
}

// ---------------- projection GEMM: C = epi(A @ Bw^T + bias) ----------------
// A fp32 reg-staged + inline cvt; Bw f16 via DMA. MT = m-tiles in grid.
template <int EPI, int MT>
__global__ __launch_bounds__(256, 4) void gemm_proj(const float* __restrict__ A,
                                                    const f16* __restrict__ Bw,
                                                    const float* __restrict__ bias,
                                                    const int* __restrict__ mask,
                                                    f16* __restrict__ C,
                                                    f16* __restrict__ pKs,
                                                    int m_base) {
  __shared__ __attribute__((aligned(16))) f16 As[128][64];
  __shared__ __attribute__((aligned(16))) f16 Bs[128][64];
  const int tid = threadIdx.x;
  const int lane = tid & 63;
  const int l15 = lane & 15, l4 = lane >> 4;
  const int w = tid >> 6, wr = w >> 1, wc = w & 1;
  int nb, mb;
  swz<MT>(nb, mb);
  const int n0 = nb * 128;
  const int c0 = mb * 128;        // local C row base
  const int m0 = m_base + c0;     // global A row base

  f32x4 acc[4][4];
#pragma unroll
  for (int j = 0; j < 4; j++) {
    float bv = bias[n0 + wc * 64 + j * 16 + l15];
#pragma unroll
    for (int i = 0; i < 4; i++) acc[i][j] = (f32x4){bv, bv, bv, bv};
  }

  for (int kt = 0; kt < DIM; kt += 64) {
    __syncthreads();
#pragma unroll
    for (int c = 0; c < 4; c++) {
      int row = w * 32 + c * 8 + (lane >> 3);
      int col = (lane & 7) * 8;
      g2l16(Bw + (size_t)(n0 + row) * DIM + kt + col, (char*)Bs + w * 4096 + c * 1024);
    }
#pragma unroll
    for (int r = 0; r < 8; r++) {
      int e = r * 1024 + tid * 4;
      int row = e >> 6, col = e & 63;
      float4 va = *(const float4*)(A + (size_t)(m0 + row) * DIM + kt + col);
      union { f16 hh[4]; uint2 u; } pa;
      pa.hh[0] = (f16)va.x; pa.hh[1] = (f16)va.y; pa.hh[2] = (f16)va.z; pa.hh[3] = (f16)va.w;
      *(uint2*)&As[row][col] = pa.u;
    }
    __syncthreads();
#pragma unroll
    for (int ks = 0; ks < 2; ks++) {
      f16x8 af[4], bfr[4];
#pragma unroll
      for (int i = 0; i < 4; i++)
        af[i] = *(f16x8*)&As[wr * 64 + i * 16 + l15][ks * 32 + l4 * 8];
#pragma unroll
      for (int j = 0; j < 4; j++)
        bfr[j] = *(f16x8*)&Bs[wc * 64 + j * 16 + l15][ks * 32 + l4 * 8];
#pragma unroll
      for (int i = 0; i < 4; i++)
#pragma unroll
        for (int j = 0; j < 4; j++)
          acc[i][j] = __builtin_amdgcn_mfma_f32_16x16x32_f16(af[i], bfr[j], acc[i][j], 0, 0, 0);
    }
  }

  float ksm[4] = {0.f, 0.f, 0.f, 0.f};
#pragma unroll
  for (int i = 0; i < 4; i++)
#pragma unroll
    for (int j = 0; j < 4; j++) {
      const int rl = wr * 64 + i * 16 + l4 * 4;
      const int gn = n0 + wc * 64 + j * 16 + l15;
#pragma unroll
      for (int r = 0; r < 4; r++) {
        int row = rl + r;
        float x = acc[i][j][r];
        if (EPI == EPI_K) {
          x = phi_f(x);
          if (mask[m0 + row] == 0) x = 0.f;
          ksm[j] += x;
        }
        C[(size_t)(c0 + row) * DIM + gn] = (f16)x;
      }
    }
  if (EPI == EPI_K) {
#pragma unroll
    for (int j = 0; j < 4; j++) {
      float v = ksm[j];
      v += __shfl_xor(v, 16);
      v += __shfl_xor(v, 32);
      if (l4 == 0)
        pKs[(size_t)(mb * 2 + wr) * 1024 + n0 + wc * 64 + j * 16 + l15] = (f16)v;
    }
  }
}

// ---------------- KV via MFMA: pKV[h][ck][d][e] = sum_{s in 512-chunk} K[s,d]*V[s,e] ----------------
// Kp points at the current half's rows; Vp is half-local.
__global__ __launch_bounds__(256) void kv_mfma(const f16* __restrict__ Kp,
                                               const f16* __restrict__ Vp,
                                               f16* __restrict__ pKV) {
  __shared__ f16 KT[64][66];
  __shared__ f16 VT[64][66];
  const int tid = threadIdx.x;
  const int lane = tid & 63;
  const int l15 = lane & 15, l4 = lane >> 4, w = tid >> 6;
  const int h = blockIdx.x;   // 16
  const int ck = blockIdx.y;  // 16 chunks of 512 rows (local half rows)
  const int bl = ck >> 3;
  const int srow0 = bl * 4096 + (ck & 7) * 512;
  const int s_loc = tid >> 2;
  const int c0 = (tid & 3) * 16;

  f32x4 acc[4];
#pragma unroll
  for (int j = 0; j < 4; j++) acc[j] = (f32x4){0.f, 0.f, 0.f, 0.f};

  for (int sub = 0; sub < 8; sub++) {
    const size_t gbase = (size_t)(srow0 + sub * 64 + s_loc) * DIM + h * 64 + c0;
    f16x8 k0 = *(const f16x8*)(Kp + gbase);
    f16x8 k1 = *(const f16x8*)(Kp + gbase + 8);
    f16x8 v0 = *(const f16x8*)(Vp + gbase);
    f16x8 v1 = *(const f16x8*)(Vp + gbase + 8);
    __syncthreads();
#pragma unroll
    for (int q = 0; q < 8; q++) {
      KT[c0 + q][s_loc] = k0[q];
      KT[c0 + 8 + q][s_loc] = k1[q];
      VT[c0 + q][s_loc] = v0[q];
      VT[c0 + 8 + q][s_loc] = v1[q];
    }
    __syncthreads();
#pragma unroll
    for (int ks = 0; ks < 2; ks++) {
      f16x8 af = *(f16x8*)&KT[w * 16 + l15][ks * 32 + l4 * 8];
#pragma unroll
      for (int j = 0; j < 4; j++) {
        f16x8 bfr = *(f16x8*)&VT[j * 16 + l15][ks * 32 + l4 * 8];
        acc[j] = __builtin_amdgcn_mfma_f32_16x16x32_f16(af, bfr, acc[j], 0, 0, 0);
      }
    }
  }
  f16* dst = pKV + (size_t)(h * 16 + ck) * 4096;
#pragma unroll
  for (int j = 0; j < 4; j++)
#pragma unroll
    for (int r = 0; r < 4; r++)
      dst[(w * 16 + l4 * 4 + r) * 64 + j * 16 + l15] = (f16)acc[j][r];
}

// ---------------- reduce: KVdh[bh][d][e] f16, Ksum[bh][d] (+eps) ----------------
// pKs is FULL-M ([256][1024]); pKV is per-half.
__global__ __launch_bounds__(256) void kv_reduce(const f16* __restrict__ pKV,
                                                 const f16* __restrict__ pKs,
                                                 f16* __restrict__ KVdh,
                                                 float* __restrict__ Ksum,
                                                 int half) {
  const int bh_l = blockIdx.x;  // 0..31
  const int h = bh_l & 15, bl = bh_l >> 4;
  const int bh = half * 32 + bh_l;
  const int b = half * 2 + bl;  // global batch
  const int tid = threadIdx.x;
  for (int cell = tid; cell < 4096; cell += 256) {
    float s = 0.f;
#pragma unroll
    for (int c = 0; c < 8; c++) s += (float)pKV[(size_t)(h * 16 + bl * 8 + c) * 4096 + cell];
    KVdh[(size_t)bh * 4096 + cell] = (f16)s;
  }
  if (tid < 64) {
    float s = 0.f;
#pragma unroll
    for (int y = 0; y < 64; y++) s += (float)pKs[(size_t)(b * 64 + y) * 1024 + h * 64 + tid];
    Ksum[bh * 64 + tid] = s + 1e-6f;  // EPS folded in
  }
}

// ---------------- M precompute: M[b][n][h*64+d] = sum_e Wo[n][h*64+e]*KV[bh][d][e] ----------------
__global__ __launch_bounds__(256) void m_kernel(const f16* __restrict__ Woh,
                                                const f16* __restrict__ KVdh,
                                                f16* __restrict__ Mh) {
  __shared__ __attribute__((aligned(16))) f16 As[128][64];
  __shared__ __attribute__((aligned(16))) f16 Bs[64][64];
  const int tid = threadIdx.x;
  const int lane = tid & 63;
  const int l15 = lane & 15, l4 = lane >> 4, w = tid >> 6;
  const int n0 = blockIdx.x * 128;
  const int bh = blockIdx.y;  // 64
  const int b = bh >> 4, h = bh & 15;

#pragma unroll
  for (int c = 0; c < 4; c++) {
    int row = w * 32 + c * 8 + (lane >> 3);
    int col = (lane & 7) * 8;
    g2l16(Woh + (size_t)(n0 + row) * DIM + h * 64 + col, (char*)As + w * 4096 + c * 1024);
  }
#pragma unroll
  for (int c = 0; c < 2; c++) {
    int row = w * 16 + c * 8 + (lane >> 3);
    int col = (lane & 7) * 8;
    g2l16(KVdh + (size_t)bh * 4096 + row * 64 + col, (char*)Bs + w * 2048 + c * 1024);
  }
  __syncthreads();

  f32x4 acc[2][4];
#pragma unroll
  for (int i = 0; i < 2; i++)
#pragma unroll
    for (int j = 0; j < 4; j++) acc[i][j] = (f32x4){0.f, 0.f, 0.f, 0.f};
#pragma unroll
  for (int ks = 0; ks < 2; ks++) {
    f16x8 af[2], bfr[4];
#pragma unroll
    for (int i = 0; i < 2; i++)
      af[i] = *(f16x8*)&As[w * 32 + i * 16 + l15][ks * 32 + l4 * 8];
#pragma unroll
    for (int j = 0; j < 4; j++)
      bfr[j] = *(f16x8*)&Bs[j * 16 + l15][ks * 32 + l4 * 8];
#pragma unroll
    for (int i = 0; i < 2; i++)
#pragma unroll
      for (int j = 0; j < 4; j++)
        acc[i][j] = __builtin_amdgcn_mfma_f32_16x16x32_f16(af[i], bfr[j], acc[i][j], 0, 0, 0);
  }
#pragma unroll
  for (int i = 0; i < 2; i++)
#pragma unroll
    for (int j = 0; j < 4; j++)
#pragma unroll
      for (int r = 0; r < 4; r++) {
        int nl = n0 + w * 32 + i * 16 + l4 * 4 + r;
        Mh[(size_t)b * 1048576 + (size_t)nl * DIM + h * 64 + j * 16 + l15] = (f16)acc[i][j][r];
      }
}

// ---------------- Q GEMM + phi + Z epilogue: Ap[s,hd] = Z_h(s)*phi(q[s,hd]), FULL-M ----------------
__global__ __launch_bounds__(256, 4) void gemm_q(const float* __restrict__ Aq,
                                                 const f16* __restrict__ Wqh,
                                                 const float* __restrict__ bq,
                                                 const float* __restrict__ Ksum,
                                                 f16* __restrict__ Ap) {
  __shared__ __attribute__((aligned(16))) char smem[32768 + 1024 + 512];
  f16 (*As)[64] = (f16(*)[64])smem;
  f16 (*Bs)[64] = (f16(*)[64])(smem + 16384);
  f16 (*Ph)[128] = (f16(*)[128])smem;            // overlay after K-loop
  float* Zlds = (float*)(smem + 32768);          // [2][128]
  float* KsumS = (float*)(smem + 32768 + 1024);  // [128]

  const int tid = threadIdx.x;
  const int lane = tid & 63;
  const int l15 = lane & 15, l4 = lane >> 4;
  const int w = tid >> 6, wr = w >> 1, wc = w & 1;
  int nb, mb;
  swz<128>(nb, mb);
  const int n0 = nb * 128;
  const int c0 = mb * 128;
  const int b = c0 >> 12;
  const int bh0 = b * 16 + nb * 2;

  if (tid < 128) KsumS[tid] = Ksum[bh0 * 64 + tid];

  f32x4 acc[4][4];
#pragma unroll
  for (int j = 0; j < 4; j++) {
    float bv = bq[n0 + wc * 64 + j * 16 + l15];
#pragma unroll
    for (int i = 0; i < 4; i++) acc[i][j] = (f32x4){bv, bv, bv, bv};
  }

  for (int kt = 0; kt < DIM; kt += 64) {
    __syncthreads();
#pragma unroll
    for (int c = 0; c < 4; c++) {
      int row = w * 32 + c * 8 + (lane >> 3);
      int col = (lane & 7) * 8;
      g2l16(Wqh + (size_t)(n0 + row) * DIM + kt + col, (char*)Bs + w * 4096 + c * 1024);
    }
#pragma unroll
    for (int r = 0; r < 8; r++) {
      int e = r * 1024 + tid * 4;
      int row = e >> 6, col = e & 63;
      float4 va = *(const float4*)(Aq + (size_t)(c0 + row) * DIM + kt + col);
      union { f16 hh[4]; uint2 u; } pa;
      pa.hh[0] = (f16)va.x; pa.hh[1] = (f16)va.y; pa.hh[2] = (f16)va.z; pa.hh[3] = (f16)va.w;
      *(uint2*)&As[row][col] = pa.u;
    }
    __syncthreads();
#pragma unroll
    for (int ks = 0; ks < 2; ks++) {
      f16x8 af[4], bfr[4];
#pragma unroll
      for (int i = 0; i < 4; i++)
        af[i] = *(f16x8*)&As[wr * 64 + i * 16 + l15][ks * 32 + l4 * 8];
#pragma unroll
      for (int j = 0; j < 4; j++)
        bfr[j] = *(f16x8*)&Bs[wc * 64 + j * 16 + l15][ks * 32 + l4 * 8];
#pragma unroll
      for (int i = 0; i < 4; i++)
#pragma unroll
        for (int j = 0; j < 4; j++)
          acc[i][j] = __builtin_amdgcn_mfma_f32_16x16x32_f16(af[i], bfr[j], acc[i][j], 0, 0, 0);
    }
  }

  __syncthreads();
#pragma unroll
  for (int i = 0; i < 4; i++)
#pragma unroll
    for (int j = 0; j < 4; j++)
#pragma unroll
      for (int r = 0; r < 4; r++) {
        int row = wr * 64 + i * 16 + l4 * 4 + r;
        int col = wc * 64 + j * 16 + l15;
        float p = phi_f(acc[i][j][r]);
        acc[i][j][r] = p;
        Ph[row][col] = (f16)p;
      }
  __syncthreads();

  if (tid < 128) {
    float den0 = 0.f, den1 = 0.f;
    for (int c = 0; c < 64; c += 8) {
      f16x8 p0 = *(f16x8*)&Ph[tid][c];
      f16x8 p1 = *(f16x8*)&Ph[tid][64 + c];
#pragma unroll
      for (int q = 0; q < 8; q++) {
        den0 += (float)p0[q] * KsumS[c + q];
        den1 += (float)p1[q] * KsumS[64 + c + q];
      }
    }
    Zlds[tid] = 1.f / den0;
    Zlds[128 + tid] = 1.f / den1;
  }
  __syncthreads();

#pragma unroll
  for (int i = 0; i < 4; i++)
#pragma unroll
    for (int j = 0; j < 4; j++)
#pragma unroll
      for (int r = 0; r < 4; r++) {
        int row = wr * 64 + i * 16 + l4 * 4 + r;
        int gn = n0 + wc * 64 + j * 16 + l15;
        float zv = Zlds[wc * 128 + row];
        Ap[(size_t)(c0 + row) * DIM + gn] = (f16)(acc[i][j][r] * zv);
      }
}

// ---------------- OUT GEMM: out = Ap @ M_b^T + bo (f16 x f16 -> f32), full DMA, FULL-M ----------------
__global__ __launch_bounds__(256, 4) void gemm_out(const f16* __restrict__ Ap,
                                                   const f16* __restrict__ Mh,
                                                   const float* __restrict__ bo,
                                                   float* __restrict__ Out) {
  __shared__ __attribute__((aligned(16))) f16 As[128][64];
  __shared__ __attribute__((aligned(16))) f16 Bs[128][64];
  const int tid = threadIdx.x;
  const int lane = tid & 63;
  const int l15 = lane & 15, l4 = lane >> 4;
  const int w = tid >> 6, wr = w >> 1, wc = w & 1;
  int nb, mb;
  swz<128>(nb, mb);
  const int n0 = nb * 128;
  const int c0 = mb * 128;
  const int b = c0 >> 12;
  const f16* B = Mh + (size_t)b * 1048576;

  f32x4 acc[4][4];
#pragma unroll
  for (int j = 0; j < 4; j++) {
    float bv = bo[n0 + wc * 64 + j * 16 + l15];
#pragma unroll
    for (int i = 0; i < 4; i++) acc[i][j] = (f32x4){bv, bv, bv, bv};
  }

  for (int kt = 0; kt < DIM; kt += 64) {
    __syncthreads();
#pragma unroll
    for (int c = 0; c < 4; c++) {
      int row = w * 32 + c * 8 + (lane >> 3);
      int col = (lane & 7) * 8;
      g2l16(Ap + (size_t)(c0 + row) * DIM + kt + col, (char*)As + w * 4096 + c * 1024);
      g2l16(B + (size_t)(n0 + row) * DIM + kt + col, (char*)Bs + w * 4096 + c * 1024);
    }
    __syncthreads();
#pragma unroll
    for (int ks = 0; ks < 2; ks++) {
      f16x8 af[4], bfr[4];
#pragma unroll
      for (int i = 0; i < 4; i++)
        af[i] = *(f16x8*)&As[wr * 64 + i * 16 + l15][ks * 32 + l4 * 8];
#pragma unroll
      for (int j = 0; j < 4; j++)
        bfr[j] = *(f16x8*)&Bs[wc * 64 + j * 16 + l15][ks * 32 + l4 * 8];
#pragma unroll
      for (int i = 0; i < 4; i++)
#pragma unroll
        for (int j = 0; j < 4; j++)
          acc[i][j] = __builtin_amdgcn_mfma_f32_16x16x32_f16(af[i], bfr[j], acc[i][j], 0, 0, 0);
    }
  }

#pragma unroll
  for (int i = 0; i < 4; i++)
#pragma unroll
    for (int j = 0; j < 4; j++) {
      const int rl = wr * 64 + i * 16 + l4 * 4;
      const int gn = n0 + wc * 64 + j * 16 + l15;
#pragma unroll
      for (int r = 0; r < 4; r++)
        Out[(size_t)(c0 + rl + r) * DIM + gn] = acc[i][j][r];
    }
}

extern "C" void kernel_launch(void* const* d_in, const int* in_sizes, int n_in,
                              void* d_out, int out_size, void* d_ws, size_t ws_size,
                              hipStream_t stream) {
  (void)in_sizes; (void)n_in; (void)out_size; (void)ws_size;
  const float* query = (const float*)d_in[0];
  const float* key = (const float*)d_in[1];
  const float* value = (const float*)d_in[2];
  const int* kmask = (const int*)d_in[3];
  const float* Wq = (const float*)d_in[4];
  const float* bq = (const float*)d_in[5];
  const float* Wk = (const float*)d_in[6];
  const float* bk = (const float*)d_in[7];
  const float* Wv = (const float*)d_in[8];
  const float* bv = (const float*)d_in[9];
  const float* Wo = (const float*)d_in[10];
  const float* bo = (const float*)d_in[11];

  // workspace (peak ~55.1 MiB; 55 MiB footprint proven in R6)
  char* ws = (char*)d_ws;
  const size_t MB = 1 << 20;
  f16* W0 = (f16*)(ws);                // 2 MiB: Wkh -> Wqh
  f16* W1 = (f16*)(ws + 2 * MB);       // 2 MiB: Wvh -> Woh
  f16* Kp = (f16*)(ws + 4 * MB);       // 32 MiB FULL ; stage2: Ap
  f16* Vp = (f16*)(ws + 36 * MB);      // 16 MiB (half) ; stage2: Mh (8 MiB)
  f16* pKV = (f16*)(ws + 52 * MB);     // 2 MiB (per-half scratch)
  f16* pKs = (f16*)(ws + 54 * MB);     // [256][1024] f16 = 512 KiB (FULL)
  f16* KVdh = (f16*)(ws + 54 * MB + 512 * 1024);      // 512 KiB
  float* Ksum = (float*)(ws + 55 * MB);               // 16 KiB
  f16* Ap = Kp;
  f16* Mh = Vp;

  dim3 blk(256);
  cvt8<<<512, blk, 0, stream>>>(Wk, W0);
  cvt8<<<512, blk, 0, stream>>>(Wv, W1);

  // stage 1: full-M K projection (1024 blocks), per-half V projection + KV
  gemm_proj<EPI_K, 128><<<dim3(8, 128), blk, 0, stream>>>(key, W0, bk, kmask, Kp, pKs, 0);
  for (int half = 0; half < 2; half++) {
    int mb = half * 8192;
    gemm_proj<EPI_V, 64><<<dim3(8, 64), blk, 0, stream>>>(value, W1, bv, nullptr, Vp, nullptr, mb);
    kv_mfma<<<dim3(16, 16), blk, 0, stream>>>(Kp + (size_t)mb * DIM, Vp, pKV);
    kv_reduce<<<32, blk, 0, stream>>>(pKV, pKs, KVdh, Ksum, half);
  }

  // stage 2: full-M Q -> A', M precompute, full-M OUT
  cvt8<<<512, blk, 0, stream>>>(Wq, W0);
  cvt8<<<512, blk, 0, stream>>>(Wo, W1);
  m_kernel<<<dim3(8, 64), blk, 0, stream>>>(W1, KVdh, Mh);
  gemm_q<<<dim3(8, 128), blk, 0, stream>>>(query, W0, bq, Ksum, Ap);
  gemm_out<<<dim3(8, 128), blk, 0, stream>>>(Ap, Mh, bo, (float*)d_out);
}

// Round 8
// 337.922 us; speedup vs baseline: 1.3019x; 1.3019x over previous
//
#include <hip/hip_runtime.h>
#include <math.h>

typedef _Float16 f16;
typedef _Float16 f16x8 __attribute__((ext_vector_type(8)));
typedef float f32x4 __attribute__((ext_vector_type(4)));

#define DIM 1024
enum { EPI_K = 0, EPI_V = 1 };

__device__ __forceinline__ float phi_f(float x) {
  return x > 0.f ? x + 1.f : __expf(x);  // elu(x)+1
}

// global -> LDS direct DMA, 16 B per lane, wave-uniform LDS base.
typedef __attribute__((address_space(1))) const void gconst_t;
typedef __attribute__((address_space(3))) void lds_t;
__device__ __forceinline__ void g2l16(const void* g, void* l) {
  __builtin_amdgcn_global_load_lds((gconst_t*)(uintptr_t)g, (lds_t*)(uintptr_t)l, 16, 0, 0);
}

// XCD-bijective swizzle for grid (8, 64) = 512 blocks.
__device__ __forceinline__ void swz_8x64(int& nb, int& mb) {
  int flat = blockIdx.y * 8 + blockIdx.x;
  int wk = (flat & 7) * 64 + (flat >> 3);
  nb = wk & 7;
  mb = wk >> 3;
}

// ---------------- fp32 -> fp16 convert (weights) ----------------
__global__ __launch_bounds__(256) void cvt8(const float* __restrict__ src,
                                            f16* __restrict__ dst) {
  size_t i = ((size_t)blockIdx.x * 256 + threadIdx.x) * 8;
  float4 a = *(const float4*)(src + i);
  float4 b = *(const float4*)(src + i + 4);
  union { f16 h[8]; uint4 u; } p;
  p.h[0] = (f16)a.x; p.h[1] = (f16)a.y; p.h[2] = (f16)a.z; p.h[3] = (f16)a.w;
  p.h[4] = (f16)b.x; p.h[5] = (f16)b.y; p.h[6] = (f16)b.z; p.h[7] = (f16)b.w;
  *(uint4*)(dst + i) = p.u;
}

// ---------------- projection GEMM: C = epi(A @ Bw^T + bias), per half ----------------
// A fp32 reg-staged + inline cvt; Bw f16 via DMA. EPI_K also emits per-64-row Ksum partials.
template <int EPI>
__global__ __launch_bounds__(256) void gemm_proj(const float* __restrict__ A,
                                                 const f16* __restrict__ Bw,
                                                 const float* __restrict__ bias,
                                                 const int* __restrict__ mask,
                                                 f16* __restrict__ C,
                                                 f16* __restrict__ pKs,
                                                 int m_base) {
  __shared__ __attribute__((aligned(16))) f16 As[128][64];
  __shared__ __attribute__((aligned(16))) f16 Bs[128][64];
  const int tid = threadIdx.x;
  const int lane = tid & 63;
  const int l15 = lane & 15, l4 = lane >> 4;
  const int w = tid >> 6, wr = w >> 1, wc = w & 1;
  int nb, mb;
  swz_8x64(nb, mb);
  const int n0 = nb * 128;
  const int c0 = mb * 128;        // local C row base
  const int m0 = m_base + c0;     // global A row base

  f32x4 acc[4][4];
#pragma unroll
  for (int j = 0; j < 4; j++) {
    float bv = bias[n0 + wc * 64 + j * 16 + l15];
#pragma unroll
    for (int i = 0; i < 4; i++) acc[i][j] = (f32x4){bv, bv, bv, bv};
  }

  for (int kt = 0; kt < DIM; kt += 64) {
    __syncthreads();
#pragma unroll
    for (int c = 0; c < 4; c++) {
      int row = w * 32 + c * 8 + (lane >> 3);
      int col = (lane & 7) * 8;
      g2l16(Bw + (size_t)(n0 + row) * DIM + kt + col, (char*)Bs + w * 4096 + c * 1024);
    }
#pragma unroll
    for (int r = 0; r < 8; r++) {
      int e = r * 1024 + tid * 4;
      int row = e >> 6, col = e & 63;
      float4 va = *(const float4*)(A + (size_t)(m0 + row) * DIM + kt + col);
      union { f16 hh[4]; uint2 u; } pa;
      pa.hh[0] = (f16)va.x; pa.hh[1] = (f16)va.y; pa.hh[2] = (f16)va.z; pa.hh[3] = (f16)va.w;
      *(uint2*)&As[row][col] = pa.u;
    }
    __syncthreads();
#pragma unroll
    for (int ks = 0; ks < 2; ks++) {
      f16x8 af[4], bfr[4];
#pragma unroll
      for (int i = 0; i < 4; i++)
        af[i] = *(f16x8*)&As[wr * 64 + i * 16 + l15][ks * 32 + l4 * 8];
#pragma unroll
      for (int j = 0; j < 4; j++)
        bfr[j] = *(f16x8*)&Bs[wc * 64 + j * 16 + l15][ks * 32 + l4 * 8];
#pragma unroll
      for (int i = 0; i < 4; i++)
#pragma unroll
        for (int j = 0; j < 4; j++)
          acc[i][j] = __builtin_amdgcn_mfma_f32_16x16x32_f16(af[i], bfr[j], acc[i][j], 0, 0, 0);
    }
  }

  float ksm[4] = {0.f, 0.f, 0.f, 0.f};
#pragma unroll
  for (int i = 0; i < 4; i++)
#pragma unroll
    for (int j = 0; j < 4; j++) {
      const int rl = wr * 64 + i * 16 + l4 * 4;
      const int gn = n0 + wc * 64 + j * 16 + l15;
#pragma unroll
      for (int r = 0; r < 4; r++) {
        int row = rl + r;
        float x = acc[i][j][r];
        if (EPI == EPI_K) {
          x = phi_f(x);
          if (mask[m0 + row] == 0) x = 0.f;
          ksm[j] += x;
        }
        C[(size_t)(c0 + row) * DIM + gn] = (f16)x;
      }
    }
  if (EPI == EPI_K) {
#pragma unroll
    for (int j = 0; j < 4; j++) {
      float v = ksm[j];
      v += __shfl_xor(v, 16);
      v += __shfl_xor(v, 32);
      if (l4 == 0)
        pKs[(size_t)(mb * 2 + wr) * 1024 + n0 + wc * 64 + j * 16 + l15] = (f16)v;
    }
  }
}

// ---------------- KV via MFMA: pKV[h][ck][d][e] = sum_{s in 512-chunk} K[s,d]*V[s,e] ----------------
__global__ __launch_bounds__(256) void kv_mfma(const f16* __restrict__ Kp,
                                               const f16* __restrict__ Vp,
                                               f16* __restrict__ pKV) {
  __shared__ f16 KT[64][66];
  __shared__ f16 VT[64][66];
  const int tid = threadIdx.x;
  const int lane = tid & 63;
  const int l15 = lane & 15, l4 = lane >> 4, w = tid >> 6;
  const int h = blockIdx.x;   // 16
  const int ck = blockIdx.y;  // 16 chunks of 512 rows (local half rows)
  const int bl = ck >> 3;
  const int srow0 = bl * 4096 + (ck & 7) * 512;
  const int s_loc = tid >> 2;
  const int c0 = (tid & 3) * 16;

  f32x4 acc[4];
#pragma unroll
  for (int j = 0; j < 4; j++) acc[j] = (f32x4){0.f, 0.f, 0.f, 0.f};

  for (int sub = 0; sub < 8; sub++) {
    const size_t gbase = (size_t)(srow0 + sub * 64 + s_loc) * DIM + h * 64 + c0;
    f16x8 k0 = *(const f16x8*)(Kp + gbase);
    f16x8 k1 = *(const f16x8*)(Kp + gbase + 8);
    f16x8 v0 = *(const f16x8*)(Vp + gbase);
    f16x8 v1 = *(const f16x8*)(Vp + gbase + 8);
    __syncthreads();
#pragma unroll
    for (int q = 0; q < 8; q++) {
      KT[c0 + q][s_loc] = k0[q];
      KT[c0 + 8 + q][s_loc] = k1[q];
      VT[c0 + q][s_loc] = v0[q];
      VT[c0 + 8 + q][s_loc] = v1[q];
    }
    __syncthreads();
#pragma unroll
    for (int ks = 0; ks < 2; ks++) {
      f16x8 af = *(f16x8*)&KT[w * 16 + l15][ks * 32 + l4 * 8];
#pragma unroll
      for (int j = 0; j < 4; j++) {
        f16x8 bfr = *(f16x8*)&VT[j * 16 + l15][ks * 32 + l4 * 8];
        acc[j] = __builtin_amdgcn_mfma_f32_16x16x32_f16(af, bfr, acc[j], 0, 0, 0);
      }
    }
  }
  f16* dst = pKV + (size_t)(h * 16 + ck) * 4096;
#pragma unroll
  for (int j = 0; j < 4; j++)
#pragma unroll
    for (int r = 0; r < 4; r++)
      dst[(w * 16 + l4 * 4 + r) * 64 + j * 16 + l15] = (f16)acc[j][r];
}

// ---------------- reduce: KVdh[bh][d][e] f16, Ksum[bh][d] (+eps) ----------------
__global__ __launch_bounds__(256) void kv_reduce(const f16* __restrict__ pKV,
                                                 const f16* __restrict__ pKs,
                                                 f16* __restrict__ KVdh,
                                                 float* __restrict__ Ksum,
                                                 int half) {
  const int bh_l = blockIdx.x;  // 0..31
  const int h = bh_l & 15, bl = bh_l >> 4;
  const int bh = half * 32 + bh_l;
  const int tid = threadIdx.x;
  for (int cell = tid; cell < 4096; cell += 256) {
    float s = 0.f;
#pragma unroll
    for (int c = 0; c < 8; c++) s += (float)pKV[(size_t)(h * 16 + bl * 8 + c) * 4096 + cell];
    KVdh[(size_t)bh * 4096 + cell] = (f16)s;
  }
  if (tid < 64) {
    float s = 0.f;
#pragma unroll
    for (int y = 0; y < 64; y++) s += (float)pKs[(size_t)(bl * 64 + y) * 1024 + h * 64 + tid];
    Ksum[bh * 64 + tid] = s + 1e-6f;  // EPS folded in
  }
}

// ---------------- M precompute: M[b][n][h*64+d] = sum_e Wo[n][h*64+e]*KV[bh][d][e] ----------------
__global__ __launch_bounds__(256) void m_kernel(const f16* __restrict__ Woh,
                                                const f16* __restrict__ KVdh,
                                                f16* __restrict__ Mh) {
  __shared__ __attribute__((aligned(16))) f16 As[128][64];
  __shared__ __attribute__((aligned(16))) f16 Bs[64][64];
  const int tid = threadIdx.x;
  const int lane = tid & 63;
  const int l15 = lane & 15, l4 = lane >> 4, w = tid >> 6;
  const int n0 = blockIdx.x * 128;
  const int bh = blockIdx.y;  // 64
  const int b = bh >> 4, h = bh & 15;

#pragma unroll
  for (int c = 0; c < 4; c++) {
    int row = w * 32 + c * 8 + (lane >> 3);
    int col = (lane & 7) * 8;
    g2l16(Woh + (size_t)(n0 + row) * DIM + h * 64 + col, (char*)As + w * 4096 + c * 1024);
  }
#pragma unroll
  for (int c = 0; c < 2; c++) {
    int row = w * 16 + c * 8 + (lane >> 3);
    int col = (lane & 7) * 8;
    g2l16(KVdh + (size_t)bh * 4096 + row * 64 + col, (char*)Bs + w * 2048 + c * 1024);
  }
  __syncthreads();

  f32x4 acc[2][4];
#pragma unroll
  for (int i = 0; i < 2; i++)
#pragma unroll
    for (int j = 0; j < 4; j++) acc[i][j] = (f32x4){0.f, 0.f, 0.f, 0.f};
#pragma unroll
  for (int ks = 0; ks < 2; ks++) {
    f16x8 af[2], bfr[4];
#pragma unroll
    for (int i = 0; i < 2; i++)
      af[i] = *(f16x8*)&As[w * 32 + i * 16 + l15][ks * 32 + l4 * 8];
#pragma unroll
    for (int j = 0; j < 4; j++)
      bfr[j] = *(f16x8*)&Bs[j * 16 + l15][ks * 32 + l4 * 8];
#pragma unroll
    for (int i = 0; i < 2; i++)
#pragma unroll
      for (int j = 0; j < 4; j++)
        acc[i][j] = __builtin_amdgcn_mfma_f32_16x16x32_f16(af[i], bfr[j], acc[i][j], 0, 0, 0);
  }
#pragma unroll
  for (int i = 0; i < 2; i++)
#pragma unroll
    for (int j = 0; j < 4; j++)
#pragma unroll
      for (int r = 0; r < 4; r++) {
        int nl = n0 + w * 32 + i * 16 + l4 * 4 + r;
        Mh[(size_t)b * 1048576 + (size_t)nl * DIM + h * 64 + j * 16 + l15] = (f16)acc[i][j][r];
      }
}

// ---------------- Q GEMM, in-register Z epilogue: Ap[s,hd] = Z_h(s)*phi(q[s,hd]) ----------------
__global__ __launch_bounds__(256) void gemm_q(const float* __restrict__ Aq,
                                              const f16* __restrict__ Wqh,
                                              const float* __restrict__ bq,
                                              const float* __restrict__ Ksum,
                                              f16* __restrict__ Ap,
                                              int m_base) {
  __shared__ __attribute__((aligned(16))) f16 As[128][64];
  __shared__ __attribute__((aligned(16))) f16 Bs[128][64];
  const int tid = threadIdx.x;
  const int lane = tid & 63;
  const int l15 = lane & 15, l4 = lane >> 4;
  const int w = tid >> 6, wr = w >> 1, wc = w & 1;
  int nb, mb;
  swz_8x64(nb, mb);
  const int n0 = nb * 128;
  const int c0 = mb * 128;
  const int m0 = m_base + c0;
  const int b = m0 >> 12;
  const int bh = b * 16 + nb * 2 + wc;  // head owned by this wave's columns

  // per-lane Ksum slice: this lane's 4 head-cols are j*16+l15
  float ks[4];
#pragma unroll
  for (int j = 0; j < 4; j++) ks[j] = Ksum[bh * 64 + j * 16 + l15];

  f32x4 acc[4][4];
#pragma unroll
  for (int j = 0; j < 4; j++) {
    float bv = bq[n0 + wc * 64 + j * 16 + l15];
#pragma unroll
    for (int i = 0; i < 4; i++) acc[i][j] = (f32x4){bv, bv, bv, bv};
  }

  for (int kt = 0; kt < DIM; kt += 64) {
    __syncthreads();
#pragma unroll
    for (int c = 0; c < 4; c++) {
      int row = w * 32 + c * 8 + (lane >> 3);
      int col = (lane & 7) * 8;
      g2l16(Wqh + (size_t)(n0 + row) * DIM + kt + col, (char*)Bs + w * 4096 + c * 1024);
    }
#pragma unroll
    for (int r = 0; r < 8; r++) {
      int e = r * 1024 + tid * 4;
      int row = e >> 6, col = e & 63;
      float4 va = *(const float4*)(Aq + (size_t)(m0 + row) * DIM + kt + col);
      union { f16 hh[4]; uint2 u; } pa;
      pa.hh[0] = (f16)va.x; pa.hh[1] = (f16)va.y; pa.hh[2] = (f16)va.z; pa.hh[3] = (f16)va.w;
      *(uint2*)&As[row][col] = pa.u;
    }
    __syncthreads();
#pragma unroll
    for (int ks2 = 0; ks2 < 2; ks2++) {
      f16x8 af[4], bfr[4];
#pragma unroll
      for (int i = 0; i < 4; i++)
        af[i] = *(f16x8*)&As[wr * 64 + i * 16 + l15][ks2 * 32 + l4 * 8];
#pragma unroll
      for (int j = 0; j < 4; j++)
        bfr[j] = *(f16x8*)&Bs[wc * 64 + j * 16 + l15][ks2 * 32 + l4 * 8];
#pragma unroll
      for (int i = 0; i < 4; i++)
#pragma unroll
        for (int j = 0; j < 4; j++)
          acc[i][j] = __builtin_amdgcn_mfma_f32_16x16x32_f16(af[i], bfr[j], acc[i][j], 0, 0, 0);
    }
  }

  // ---- in-register epilogue: phi, den via 16-lane shuffle reduce, Z-scale, write ----
  // row = wr*64+i*16+l4*4+r is constant across the 16-lane l15 group (xor masks 1,2,4,8
  // only permute lane bits 0-3), so den reduces over exactly this head's 64 cols.
#pragma unroll
  for (int i = 0; i < 4; i++) {
#pragma unroll
    for (int r = 0; r < 4; r++) {
      float p0 = phi_f(acc[i][0][r]);
      float p1 = phi_f(acc[i][1][r]);
      float p2 = phi_f(acc[i][2][r]);
      float p3 = phi_f(acc[i][3][r]);
      float den = p0 * ks[0] + p1 * ks[1] + p2 * ks[2] + p3 * ks[3];
      den += __shfl_xor(den, 1);
      den += __shfl_xor(den, 2);
      den += __shfl_xor(den, 4);
      den += __shfl_xor(den, 8);
      float z = 1.f / den;
      int row = wr * 64 + i * 16 + l4 * 4 + r;
      size_t base = (size_t)(c0 + row) * DIM + n0 + wc * 64 + l15;
      Ap[base] = (f16)(p0 * z);
      Ap[base + 16] = (f16)(p1 * z);
      Ap[base + 32] = (f16)(p2 * z);
      Ap[base + 48] = (f16)(p3 * z);
    }
  }
}

// ---------------- OUT GEMM: out = Ap @ M_b^T + bo (f16 x f16 -> f32), full DMA, per half ----------------
__global__ __launch_bounds__(256) void gemm_out(const f16* __restrict__ Ap,
                                                const f16* __restrict__ Mh,
                                                const float* __restrict__ bo,
                                                float* __restrict__ Out,
                                                int m_base) {
  __shared__ __attribute__((aligned(16))) f16 As[128][64];
  __shared__ __attribute__((aligned(16))) f16 Bs[128][64];
  const int tid = threadIdx.x;
  const int lane = tid & 63;
  const int l15 = lane & 15, l4 = lane >> 4;
  const int w = tid >> 6, wr = w >> 1, wc = w & 1;
  int nb, mb;
  swz_8x64(nb, mb);
  const int n0 = nb * 128;
  const int c0 = mb * 128;
  const int b = (m_base + c0) >> 12;
  const f16* B = Mh + (size_t)b * 1048576;

  f32x4 acc[4][4];
#pragma unroll
  for (int j = 0; j < 4; j++) {
    float bv = bo[n0 + wc * 64 + j * 16 + l15];
#pragma unroll
    for (int i = 0; i < 4; i++) acc[i][j] = (f32x4){bv, bv, bv, bv};
  }

  for (int kt = 0; kt < DIM; kt += 64) {
    __syncthreads();
#pragma unroll
    for (int c = 0; c < 4; c++) {
      int row = w * 32 + c * 8 + (lane >> 3);
      int col = (lane & 7) * 8;
      g2l16(Ap + (size_t)(c0 + row) * DIM + kt + col, (char*)As + w * 4096 + c * 1024);
      g2l16(B + (size_t)(n0 + row) * DIM + kt + col, (char*)Bs + w * 4096 + c * 1024);
    }
    __syncthreads();
#pragma unroll
    for (int ks = 0; ks < 2; ks++) {
      f16x8 af[4], bfr[4];
#pragma unroll
      for (int i = 0; i < 4; i++)
        af[i] = *(f16x8*)&As[wr * 64 + i * 16 + l15][ks * 32 + l4 * 8];
#pragma unroll
      for (int j = 0; j < 4; j++)
        bfr[j] = *(f16x8*)&Bs[wc * 64 + j * 16 + l15][ks * 32 + l4 * 8];
#pragma unroll
      for (int i = 0; i < 4; i++)
#pragma unroll
        for (int j = 0; j < 4; j++)
          acc[i][j] = __builtin_amdgcn_mfma_f32_16x16x32_f16(af[i], bfr[j], acc[i][j], 0, 0, 0);
    }
  }

#pragma unroll
  for (int i = 0; i < 4; i++)
#pragma unroll
    for (int j = 0; j < 4; j++) {
      const int rl = wr * 64 + i * 16 + l4 * 4;
      const int gn = n0 + wc * 64 + j * 16 + l15;
#pragma unroll
      for (int r = 0; r < 4; r++)
        Out[(size_t)(m_base + c0 + rl + r) * DIM + gn] = acc[i][j][r];
    }
}

extern "C" void kernel_launch(void* const* d_in, const int* in_sizes, int n_in,
                              void* d_out, int out_size, void* d_ws, size_t ws_size,
                              hipStream_t stream) {
  (void)in_sizes; (void)n_in; (void)out_size; (void)ws_size;
  const float* query = (const float*)d_in[0];
  const float* key = (const float*)d_in[1];
  const float* value = (const float*)d_in[2];
  const int* kmask = (const int*)d_in[3];
  const float* Wq = (const float*)d_in[4];
  const float* bq = (const float*)d_in[5];
  const float* Wk = (const float*)d_in[6];
  const float* bk = (const float*)d_in[7];
  const float* Wv = (const float*)d_in[8];
  const float* bv = (const float*)d_in[9];
  const float* Wo = (const float*)d_in[10];
  const float* bo = (const float*)d_in[11];

  // workspace (peak ~38.8 MiB; proven safe)
  char* ws = (char*)d_ws;
  const size_t MB = 1 << 20;
  f16* W0 = (f16*)(ws);               // Wkh -> Wqh
  f16* W1 = (f16*)(ws + 2 * MB);      // Wvh -> Woh
  f16* Kp = (f16*)(ws + 4 * MB);      // 16 MiB (half) ; stage2: Ap
  f16* Vp = (f16*)(ws + 20 * MB);     // 16 MiB (half) ; stage2: Mh (8 MiB)
  f16* pKV = (f16*)(ws + 36 * MB);    // 2 MiB (per-half scratch)
  f16* pKs = (f16*)(ws + 38 * MB);    // [128][1024] f16 = 256 KiB (per-half scratch)
  f16* KVdh = (f16*)(ws + 38 * MB + 256 * 1024);      // 512 KiB
  float* Ksum = (float*)(ws + 38 * MB + 768 * 1024);  // 16 KiB
  f16* Ap = Kp;
  f16* Mh = Vp;

  dim3 blk(256);
  cvt8<<<512, blk, 0, stream>>>(Wk, W0);
  cvt8<<<512, blk, 0, stream>>>(Wv, W1);

  // stage 1: per-half K/V projections + MFMA KV partials
  for (int half = 0; half < 2; half++) {
    int mb = half * 8192;
    gemm_proj<EPI_K><<<dim3(8, 64), blk, 0, stream>>>(key, W0, bk, kmask, Kp, pKs, mb);
    gemm_proj<EPI_V><<<dim3(8, 64), blk, 0, stream>>>(value, W1, bv, nullptr, Vp, nullptr, mb);
    kv_mfma<<<dim3(16, 16), blk, 0, stream>>>(Kp, Vp, pKV);
    kv_reduce<<<32, blk, 0, stream>>>(pKV, pKs, KVdh, Ksum, half);
  }

  // stage 2
  cvt8<<<512, blk, 0, stream>>>(Wq, W0);
  cvt8<<<512, blk, 0, stream>>>(Wo, W1);
  m_kernel<<<dim3(8, 64), blk, 0, stream>>>(W1, KVdh, Mh);
  for (int half = 0; half < 2; half++) {
    int mb = half * 8192;
    gemm_q<<<dim3(8, 64), blk, 0, stream>>>(query, W0, bq, Ksum, Ap, mb);
    gemm_out<<<dim3(8, 64), blk, 0, stream>>>(Ap, Mh, bo, (float*)d_out, mb);
  }
}

// Round 9
// 333.954 us; speedup vs baseline: 1.3173x; 1.0119x over previous
//
#include <hip/hip_runtime.h>
#include <math.h>

typedef _Float16 f16;
typedef _Float16 f16x8 __attribute__((ext_vector_type(8)));
typedef float f32x4 __attribute__((ext_vector_type(4)));

#define DIM 1024
enum { EPI_K = 0, EPI_V = 1 };

__device__ __forceinline__ float phi_f(float x) {
  return x > 0.f ? x + 1.f : __expf(x);  // elu(x)+1
}

// global -> LDS direct DMA, 16 B per lane, wave-uniform LDS base.
typedef __attribute__((address_space(1))) const void gconst_t;
typedef __attribute__((address_space(3))) void lds_t;
__device__ __forceinline__ void g2l16(const void* g, void* l) {
  __builtin_amdgcn_global_load_lds((gconst_t*)(uintptr_t)g, (lds_t*)(uintptr_t)l, 16, 0, 0);
}

// XCD-bijective swizzle for grid (8, MT): XCD x gets MT/8 consecutive m-tiles x all 8 n-tiles.
template <int MT>
__device__ __forceinline__ void swz(int& nb, int& mb) {
  int flat = blockIdx.y * 8 + blockIdx.x;
  int wk = (flat & 7) * MT + (flat >> 3);
  nb = wk & 7;
  mb = wk >> 3;
}

// ---------------- fp32 -> fp16 convert (weights) ----------------
__global__ __launch_bounds__(256) void cvt8(const float* __restrict__ src,
                                            f16* __restrict__ dst) {
  size_t i = ((size_t)blockIdx.x * 256 + threadIdx.x) * 8;
  float4 a = *(const float4*)(src + i);
  float4 b = *(const float4*)(src + i + 4);
  union { f16 h[8]; uint4 u; } p;
  p.h[0] = (f16)a.x; p.h[1] = (f16)a.y; p.h[2] = (f16)a.z; p.h[3] = (f16)a.w;
  p.h[4] = (f16)b.x; p.h[5] = (f16)b.y; p.h[6] = (f16)b.z; p.h[7] = (f16)b.w;
  *(uint4*)(dst + i) = p.u;
}

// ---------------- projection GEMM: C = epi(A @ Bw^T + bias) ----------------
// A fp32 reg-staged + inline cvt; Bw f16 via DMA. MT = m-tiles in grid (natural VGPR budget).
template <int EPI, int MT>
__global__ __launch_bounds__(256) void gemm_proj(const float* __restrict__ A,
                                                 const f16* __restrict__ Bw,
                                                 const float* __restrict__ bias,
                                                 const int* __restrict__ mask,
                                                 f16* __restrict__ C,
                                                 f16* __restrict__ pKs,
                                                 int m_base) {
  __shared__ __attribute__((aligned(16))) f16 As[128][64];
  __shared__ __attribute__((aligned(16))) f16 Bs[128][64];
  const int tid = threadIdx.x;
  const int lane = tid & 63;
  const int l15 = lane & 15, l4 = lane >> 4;
  const int w = tid >> 6, wr = w >> 1, wc = w & 1;
  int nb, mb;
  swz<MT>(nb, mb);
  const int n0 = nb * 128;
  const int c0 = mb * 128;        // local C row base
  const int m0 = m_base + c0;     // global A row base

  f32x4 acc[4][4];
#pragma unroll
  for (int j = 0; j < 4; j++) {
    float bv = bias[n0 + wc * 64 + j * 16 + l15];
#pragma unroll
    for (int i = 0; i < 4; i++) acc[i][j] = (f32x4){bv, bv, bv, bv};
  }

  for (int kt = 0; kt < DIM; kt += 64) {
    __syncthreads();
#pragma unroll
    for (int c = 0; c < 4; c++) {
      int row = w * 32 + c * 8 + (lane >> 3);
      int col = (lane & 7) * 8;
      g2l16(Bw + (size_t)(n0 + row) * DIM + kt + col, (char*)Bs + w * 4096 + c * 1024);
    }
#pragma unroll
    for (int r = 0; r < 8; r++) {
      int e = r * 1024 + tid * 4;
      int row = e >> 6, col = e & 63;
      float4 va = *(const float4*)(A + (size_t)(m0 + row) * DIM + kt + col);
      union { f16 hh[4]; uint2 u; } pa;
      pa.hh[0] = (f16)va.x; pa.hh[1] = (f16)va.y; pa.hh[2] = (f16)va.z; pa.hh[3] = (f16)va.w;
      *(uint2*)&As[row][col] = pa.u;
    }
    __syncthreads();
#pragma unroll
    for (int ks = 0; ks < 2; ks++) {
      f16x8 af[4], bfr[4];
#pragma unroll
      for (int i = 0; i < 4; i++)
        af[i] = *(f16x8*)&As[wr * 64 + i * 16 + l15][ks * 32 + l4 * 8];
#pragma unroll
      for (int j = 0; j < 4; j++)
        bfr[j] = *(f16x8*)&Bs[wc * 64 + j * 16 + l15][ks * 32 + l4 * 8];
#pragma unroll
      for (int i = 0; i < 4; i++)
#pragma unroll
        for (int j = 0; j < 4; j++)
          acc[i][j] = __builtin_amdgcn_mfma_f32_16x16x32_f16(af[i], bfr[j], acc[i][j], 0, 0, 0);
    }
  }

  float ksm[4] = {0.f, 0.f, 0.f, 0.f};
#pragma unroll
  for (int i = 0; i < 4; i++)
#pragma unroll
    for (int j = 0; j < 4; j++) {
      const int rl = wr * 64 + i * 16 + l4 * 4;
      const int gn = n0 + wc * 64 + j * 16 + l15;
#pragma unroll
      for (int r = 0; r < 4; r++) {
        int row = rl + r;
        float x = acc[i][j][r];
        if (EPI == EPI_K) {
          x = phi_f(x);
          if (mask[m0 + row] == 0) x = 0.f;
          ksm[j] += x;
        }
        C[(size_t)(c0 + row) * DIM + gn] = (f16)x;
      }
    }
  if (EPI == EPI_K) {
#pragma unroll
    for (int j = 0; j < 4; j++) {
      float v = ksm[j];
      v += __shfl_xor(v, 16);
      v += __shfl_xor(v, 32);
      if (l4 == 0)
        pKs[(size_t)(mb * 2 + wr) * 1024 + n0 + wc * 64 + j * 16 + l15] = (f16)v;
    }
  }
}

// ---------------- KV via MFMA: pKV[h][ck][d][e] = sum_{s in 512-chunk} K[s,d]*V[s,e] ----------------
// Kp points at the current half's rows; Vp is half-local.
__global__ __launch_bounds__(256) void kv_mfma(const f16* __restrict__ Kp,
                                               const f16* __restrict__ Vp,
                                               f16* __restrict__ pKV) {
  __shared__ f16 KT[64][66];
  __shared__ f16 VT[64][66];
  const int tid = threadIdx.x;
  const int lane = tid & 63;
  const int l15 = lane & 15, l4 = lane >> 4, w = tid >> 6;
  const int h = blockIdx.x;   // 16
  const int ck = blockIdx.y;  // 16 chunks of 512 rows (local half rows)
  const int bl = ck >> 3;
  const int srow0 = bl * 4096 + (ck & 7) * 512;
  const int s_loc = tid >> 2;
  const int c0 = (tid & 3) * 16;

  f32x4 acc[4];
#pragma unroll
  for (int j = 0; j < 4; j++) acc[j] = (f32x4){0.f, 0.f, 0.f, 0.f};

  for (int sub = 0; sub < 8; sub++) {
    const size_t gbase = (size_t)(srow0 + sub * 64 + s_loc) * DIM + h * 64 + c0;
    f16x8 k0 = *(const f16x8*)(Kp + gbase);
    f16x8 k1 = *(const f16x8*)(Kp + gbase + 8);
    f16x8 v0 = *(const f16x8*)(Vp + gbase);
    f16x8 v1 = *(const f16x8*)(Vp + gbase + 8);
    __syncthreads();
#pragma unroll
    for (int q = 0; q < 8; q++) {
      KT[c0 + q][s_loc] = k0[q];
      KT[c0 + 8 + q][s_loc] = k1[q];
      VT[c0 + q][s_loc] = v0[q];
      VT[c0 + 8 + q][s_loc] = v1[q];
    }
    __syncthreads();
#pragma unroll
    for (int ks = 0; ks < 2; ks++) {
      f16x8 af = *(f16x8*)&KT[w * 16 + l15][ks * 32 + l4 * 8];
#pragma unroll
      for (int j = 0; j < 4; j++) {
        f16x8 bfr = *(f16x8*)&VT[j * 16 + l15][ks * 32 + l4 * 8];
        acc[j] = __builtin_amdgcn_mfma_f32_16x16x32_f16(af, bfr, acc[j], 0, 0, 0);
      }
    }
  }
  f16* dst = pKV + (size_t)(h * 16 + ck) * 4096;
#pragma unroll
  for (int j = 0; j < 4; j++)
#pragma unroll
    for (int r = 0; r < 4; r++)
      dst[(w * 16 + l4 * 4 + r) * 64 + j * 16 + l15] = (f16)acc[j][r];
}

// ---------------- reduce: KVdh[bh][d][e] f16, Ksum[bh][d] (+eps) ----------------
// pKs is FULL-M ([256][1024]); pKV is per-half.
__global__ __launch_bounds__(256) void kv_reduce(const f16* __restrict__ pKV,
                                                 const f16* __restrict__ pKs,
                                                 f16* __restrict__ KVdh,
                                                 float* __restrict__ Ksum,
                                                 int half) {
  const int bh_l = blockIdx.x;  // 0..31
  const int h = bh_l & 15, bl = bh_l >> 4;
  const int bh = half * 32 + bh_l;
  const int b = half * 2 + bl;  // global batch
  const int tid = threadIdx.x;
  for (int cell = tid; cell < 4096; cell += 256) {
    float s = 0.f;
#pragma unroll
    for (int c = 0; c < 8; c++) s += (float)pKV[(size_t)(h * 16 + bl * 8 + c) * 4096 + cell];
    KVdh[(size_t)bh * 4096 + cell] = (f16)s;
  }
  if (tid < 64) {
    float s = 0.f;
#pragma unroll
    for (int y = 0; y < 64; y++) s += (float)pKs[(size_t)(b * 64 + y) * 1024 + h * 64 + tid];
    Ksum[bh * 64 + tid] = s + 1e-6f;  // EPS folded in
  }
}

// ---------------- M precompute: M[b][n][h*64+d] = sum_e Wo[n][h*64+e]*KV[bh][d][e] ----------------
__global__ __launch_bounds__(256) void m_kernel(const f16* __restrict__ Woh,
                                                const f16* __restrict__ KVdh,
                                                f16* __restrict__ Mh) {
  __shared__ __attribute__((aligned(16))) f16 As[128][64];
  __shared__ __attribute__((aligned(16))) f16 Bs[64][64];
  const int tid = threadIdx.x;
  const int lane = tid & 63;
  const int l15 = lane & 15, l4 = lane >> 4, w = tid >> 6;
  const int n0 = blockIdx.x * 128;
  const int bh = blockIdx.y;  // 64
  const int b = bh >> 4, h = bh & 15;

#pragma unroll
  for (int c = 0; c < 4; c++) {
    int row = w * 32 + c * 8 + (lane >> 3);
    int col = (lane & 7) * 8;
    g2l16(Woh + (size_t)(n0 + row) * DIM + h * 64 + col, (char*)As + w * 4096 + c * 1024);
  }
#pragma unroll
  for (int c = 0; c < 2; c++) {
    int row = w * 16 + c * 8 + (lane >> 3);
    int col = (lane & 7) * 8;
    g2l16(KVdh + (size_t)bh * 4096 + row * 64 + col, (char*)Bs + w * 2048 + c * 1024);
  }
  __syncthreads();

  f32x4 acc[2][4];
#pragma unroll
  for (int i = 0; i < 2; i++)
#pragma unroll
    for (int j = 0; j < 4; j++) acc[i][j] = (f32x4){0.f, 0.f, 0.f, 0.f};
#pragma unroll
  for (int ks = 0; ks < 2; ks++) {
    f16x8 af[2], bfr[4];
#pragma unroll
    for (int i = 0; i < 2; i++)
      af[i] = *(f16x8*)&As[w * 32 + i * 16 + l15][ks * 32 + l4 * 8];
#pragma unroll
    for (int j = 0; j < 4; j++)
      bfr[j] = *(f16x8*)&Bs[j * 16 + l15][ks * 32 + l4 * 8];
#pragma unroll
    for (int i = 0; i < 2; i++)
#pragma unroll
      for (int j = 0; j < 4; j++)
        acc[i][j] = __builtin_amdgcn_mfma_f32_16x16x32_f16(af[i], bfr[j], acc[i][j], 0, 0, 0);
  }
#pragma unroll
  for (int i = 0; i < 2; i++)
#pragma unroll
    for (int j = 0; j < 4; j++)
#pragma unroll
      for (int r = 0; r < 4; r++) {
        int nl = n0 + w * 32 + i * 16 + l4 * 4 + r;
        Mh[(size_t)b * 1048576 + (size_t)nl * DIM + h * 64 + j * 16 + l15] = (f16)acc[i][j][r];
      }
}

// ---------------- Q GEMM, in-register Z epilogue: Ap[s,hd] = Z_h(s)*phi(q[s,hd]), FULL-M ----------------
__global__ __launch_bounds__(256) void gemm_q(const float* __restrict__ Aq,
                                              const f16* __restrict__ Wqh,
                                              const float* __restrict__ bq,
                                              const float* __restrict__ Ksum,
                                              f16* __restrict__ Ap) {
  __shared__ __attribute__((aligned(16))) f16 As[128][64];
  __shared__ __attribute__((aligned(16))) f16 Bs[128][64];
  const int tid = threadIdx.x;
  const int lane = tid & 63;
  const int l15 = lane & 15, l4 = lane >> 4;
  const int w = tid >> 6, wr = w >> 1, wc = w & 1;
  int nb, mb;
  swz<128>(nb, mb);
  const int n0 = nb * 128;
  const int c0 = mb * 128;
  const int b = c0 >> 12;
  const int bh = b * 16 + nb * 2 + wc;  // head owned by this wave's columns

  // per-lane Ksum slice: this lane's 4 head-cols are j*16+l15
  float ks[4];
#pragma unroll
  for (int j = 0; j < 4; j++) ks[j] = Ksum[bh * 64 + j * 16 + l15];

  f32x4 acc[4][4];
#pragma unroll
  for (int j = 0; j < 4; j++) {
    float bv = bq[n0 + wc * 64 + j * 16 + l15];
#pragma unroll
    for (int i = 0; i < 4; i++) acc[i][j] = (f32x4){bv, bv, bv, bv};
  }

  for (int kt = 0; kt < DIM; kt += 64) {
    __syncthreads();
#pragma unroll
    for (int c = 0; c < 4; c++) {
      int row = w * 32 + c * 8 + (lane >> 3);
      int col = (lane & 7) * 8;
      g2l16(Wqh + (size_t)(n0 + row) * DIM + kt + col, (char*)Bs + w * 4096 + c * 1024);
    }
#pragma unroll
    for (int r = 0; r < 8; r++) {
      int e = r * 1024 + tid * 4;
      int row = e >> 6, col = e & 63;
      float4 va = *(const float4*)(Aq + (size_t)(c0 + row) * DIM + kt + col);
      union { f16 hh[4]; uint2 u; } pa;
      pa.hh[0] = (f16)va.x; pa.hh[1] = (f16)va.y; pa.hh[2] = (f16)va.z; pa.hh[3] = (f16)va.w;
      *(uint2*)&As[row][col] = pa.u;
    }
    __syncthreads();
#pragma unroll
    for (int ks2 = 0; ks2 < 2; ks2++) {
      f16x8 af[4], bfr[4];
#pragma unroll
      for (int i = 0; i < 4; i++)
        af[i] = *(f16x8*)&As[wr * 64 + i * 16 + l15][ks2 * 32 + l4 * 8];
#pragma unroll
      for (int j = 0; j < 4; j++)
        bfr[j] = *(f16x8*)&Bs[wc * 64 + j * 16 + l15][ks2 * 32 + l4 * 8];
#pragma unroll
      for (int i = 0; i < 4; i++)
#pragma unroll
        for (int j = 0; j < 4; j++)
          acc[i][j] = __builtin_amdgcn_mfma_f32_16x16x32_f16(af[i], bfr[j], acc[i][j], 0, 0, 0);
    }
  }

  // ---- in-register epilogue: phi, den via 16-lane shuffle reduce, Z-scale, write ----
#pragma unroll
  for (int i = 0; i < 4; i++) {
#pragma unroll
    for (int r = 0; r < 4; r++) {
      float p0 = phi_f(acc[i][0][r]);
      float p1 = phi_f(acc[i][1][r]);
      float p2 = phi_f(acc[i][2][r]);
      float p3 = phi_f(acc[i][3][r]);
      float den = p0 * ks[0] + p1 * ks[1] + p2 * ks[2] + p3 * ks[3];
      den += __shfl_xor(den, 1);
      den += __shfl_xor(den, 2);
      den += __shfl_xor(den, 4);
      den += __shfl_xor(den, 8);
      float z = 1.f / den;
      int row = wr * 64 + i * 16 + l4 * 4 + r;
      size_t base = (size_t)(c0 + row) * DIM + n0 + wc * 64 + l15;
      Ap[base] = (f16)(p0 * z);
      Ap[base + 16] = (f16)(p1 * z);
      Ap[base + 32] = (f16)(p2 * z);
      Ap[base + 48] = (f16)(p3 * z);
    }
  }
}

// ---------------- OUT GEMM: out = Ap @ M_b^T + bo (f16 x f16 -> f32), full DMA, FULL-M ----------------
__global__ __launch_bounds__(256) void gemm_out(const f16* __restrict__ Ap,
                                                const f16* __restrict__ Mh,
                                                const float* __restrict__ bo,
                                                float* __restrict__ Out) {
  __shared__ __attribute__((aligned(16))) f16 As[128][64];
  __shared__ __attribute__((aligned(16))) f16 Bs[128][64];
  const int tid = threadIdx.x;
  const int lane = tid & 63;
  const int l15 = lane & 15, l4 = lane >> 4;
  const int w = tid >> 6, wr = w >> 1, wc = w & 1;
  int nb, mb;
  swz<128>(nb, mb);
  const int n0 = nb * 128;
  const int c0 = mb * 128;
  const int b = c0 >> 12;
  const f16* B = Mh + (size_t)b * 1048576;

  f32x4 acc[4][4];
#pragma unroll
  for (int j = 0; j < 4; j++) {
    float bv = bo[n0 + wc * 64 + j * 16 + l15];
#pragma unroll
    for (int i = 0; i < 4; i++) acc[i][j] = (f32x4){bv, bv, bv, bv};
  }

  for (int kt = 0; kt < DIM; kt += 64) {
    __syncthreads();
#pragma unroll
    for (int c = 0; c < 4; c++) {
      int row = w * 32 + c * 8 + (lane >> 3);
      int col = (lane & 7) * 8;
      g2l16(Ap + (size_t)(c0 + row) * DIM + kt + col, (char*)As + w * 4096 + c * 1024);
      g2l16(B + (size_t)(n0 + row) * DIM + kt + col, (char*)Bs + w * 4096 + c * 1024);
    }
    __syncthreads();
#pragma unroll
    for (int ks = 0; ks < 2; ks++) {
      f16x8 af[4], bfr[4];
#pragma unroll
      for (int i = 0; i < 4; i++)
        af[i] = *(f16x8*)&As[wr * 64 + i * 16 + l15][ks * 32 + l4 * 8];
#pragma unroll
      for (int j = 0; j < 4; j++)
        bfr[j] = *(f16x8*)&Bs[wc * 64 + j * 16 + l15][ks * 32 + l4 * 8];
#pragma unroll
      for (int i = 0; i < 4; i++)
#pragma unroll
        for (int j = 0; j < 4; j++)
          acc[i][j] = __builtin_amdgcn_mfma_f32_16x16x32_f16(af[i], bfr[j], acc[i][j], 0, 0, 0);
    }
  }

#pragma unroll
  for (int i = 0; i < 4; i++)
#pragma unroll
    for (int j = 0; j < 4; j++) {
      const int rl = wr * 64 + i * 16 + l4 * 4;
      const int gn = n0 + wc * 64 + j * 16 + l15;
#pragma unroll
      for (int r = 0; r < 4; r++)
        Out[(size_t)(c0 + rl + r) * DIM + gn] = acc[i][j][r];
    }
}

extern "C" void kernel_launch(void* const* d_in, const int* in_sizes, int n_in,
                              void* d_out, int out_size, void* d_ws, size_t ws_size,
                              hipStream_t stream) {
  (void)in_sizes; (void)n_in; (void)out_size; (void)ws_size;
  const float* query = (const float*)d_in[0];
  const float* key = (const float*)d_in[1];
  const float* value = (const float*)d_in[2];
  const int* kmask = (const int*)d_in[3];
  const float* Wq = (const float*)d_in[4];
  const float* bq = (const float*)d_in[5];
  const float* Wk = (const float*)d_in[6];
  const float* bk = (const float*)d_in[7];
  const float* Wv = (const float*)d_in[8];
  const float* bv = (const float*)d_in[9];
  const float* Wo = (const float*)d_in[10];
  const float* bo = (const float*)d_in[11];

  // workspace (peak ~55.1 MiB; exact R7 layout, proven safe)
  char* ws = (char*)d_ws;
  const size_t MB = 1 << 20;
  f16* W0 = (f16*)(ws);                // 2 MiB: Wkh -> Wqh
  f16* W1 = (f16*)(ws + 2 * MB);       // 2 MiB: Wvh -> Woh
  f16* Kp = (f16*)(ws + 4 * MB);       // 32 MiB FULL ; stage2: Ap
  f16* Vp = (f16*)(ws + 36 * MB);      // 16 MiB (half) ; stage2: Mh (8 MiB)
  f16* pKV = (f16*)(ws + 52 * MB);     // 2 MiB (per-half scratch)
  f16* pKs = (f16*)(ws + 54 * MB);     // [256][1024] f16 = 512 KiB (FULL)
  f16* KVdh = (f16*)(ws + 54 * MB + 512 * 1024);      // 512 KiB
  float* Ksum = (float*)(ws + 55 * MB);               // 16 KiB
  f16* Ap = Kp;
  f16* Mh = Vp;

  dim3 blk(256);
  cvt8<<<512, blk, 0, stream>>>(Wk, W0);
  cvt8<<<512, blk, 0, stream>>>(Wv, W1);

  // stage 1: full-M K projection (1024 blocks, natural VGPR), per-half V projection + KV
  gemm_proj<EPI_K, 128><<<dim3(8, 128), blk, 0, stream>>>(key, W0, bk, kmask, Kp, pKs, 0);
  for (int half = 0; half < 2; half++) {
    int mb = half * 8192;
    gemm_proj<EPI_V, 64><<<dim3(8, 64), blk, 0, stream>>>(value, W1, bv, nullptr, Vp, nullptr, mb);
    kv_mfma<<<dim3(16, 16), blk, 0, stream>>>(Kp + (size_t)mb * DIM, Vp, pKV);
    kv_reduce<<<32, blk, 0, stream>>>(pKV, pKs, KVdh, Ksum, half);
  }

  // stage 2: full-M Q -> A', M precompute, full-M OUT
  cvt8<<<512, blk, 0, stream>>>(Wq, W0);
  cvt8<<<512, blk, 0, stream>>>(Wo, W1);
  m_kernel<<<dim3(8, 64), blk, 0, stream>>>(W1, KVdh, Mh);
  gemm_q<<<dim3(8, 128), blk, 0, stream>>>(query, W0, bq, Ksum, Ap);
  gemm_out<<<dim3(8, 128), blk, 0, stream>>>(Ap, Mh, bo, (float*)d_out);
}